// Round 2
// baseline (739.673 us; speedup 1.0000x reference)
//
#include <hip/hip_runtime.h>
#include <hip/hip_bf16.h>
#include <stdint.h>

#define HID 2048
#define NHEAD 16
#define DHEAD 128
#define BB 2
#define SS 2048
#define MM (BB*SS)       // 4096
#define NQKV (3*HID)     // 6144

typedef __attribute__((ext_vector_type(8))) short bf16x8;
typedef __attribute__((ext_vector_type(4))) float f32x4;
typedef unsigned short ushort_t;

__device__ __forceinline__ f32x4 mfma16(bf16x8 a, bf16x8 b, f32x4 c) {
    return __builtin_amdgcn_mfma_f32_16x16x32_bf16(a, b, c, 0, 0, 0);
}

__device__ __forceinline__ float bf2f(ushort_t u) {
    unsigned int x = ((unsigned int)u) << 16;
    return __builtin_bit_cast(float, x);
}
__device__ __forceinline__ ushort_t f2bf(float f) {
    unsigned int x = __builtin_bit_cast(unsigned int, f);
    unsigned int r = (x + 0x7FFFu + ((x >> 16) & 1u)) >> 16;
    return (ushort_t)r;
}

// load 8 contiguous f32, round to bf16, store as one 16B LDS chunk
__device__ __forceinline__ void cvt8(const float* __restrict__ g, ushort_t* l) {
    float4 a = *(const float4*)g;
    float4 b = *(const float4*)(g + 4);
    union { ushort_t u[8]; uint4 v; } t;
    t.u[0] = f2bf(a.x); t.u[1] = f2bf(a.y); t.u[2] = f2bf(a.z); t.u[3] = f2bf(a.w);
    t.u[4] = f2bf(b.x); t.u[5] = f2bf(b.y); t.u[6] = f2bf(b.z); t.u[7] = f2bf(b.w);
    *(uint4*)l = t.v;
}

// ---------------------------------------------------------------------------
// Kernel 1: QKV GEMM.  C[m][n] = sum_k X[m][k]*W[n][k] + bias[n]   (f32 in)
// 128x128 tile, BK=32, 256 threads (4 waves, 2x2 of 64x64 each).
// Epilogue scatters bf16: n in [0,2048)->q[b][h][s][d]; [2048,4096)->k;
// [4096,6144)->vT[b][h][d][s]
// ---------------------------------------------------------------------------
#define LDA 40   // 32 + 8 pad

__global__ __launch_bounds__(256, 2) void qkv_gemm_kernel(
    const float* __restrict__ X,
    const float* __restrict__ W,
    const float* __restrict__ bias,
    ushort_t* __restrict__ qws,
    ushort_t* __restrict__ kws,
    ushort_t* __restrict__ vtws)
{
    __shared__ __align__(16) ushort_t As[128 * LDA];
    __shared__ __align__(16) ushort_t Bs[128 * LDA];
    const int tid  = threadIdx.x;
    const int lane = tid & 63;
    const int w    = tid >> 6;
    const int wm   = w >> 1, wn = w & 1;
    const int quad = lane >> 4;
    const int l15  = lane & 15;
    const int m0 = blockIdx.y * 128;
    const int n0 = blockIdx.x * 128;

    f32x4 acc[4][4];
    for (int i = 0; i < 4; i++)
        for (int j = 0; j < 4; j++)
            for (int e = 0; e < 4; e++) acc[i][j][e] = 0.f;

    for (int k0 = 0; k0 < HID; k0 += 32) {
        __syncthreads();
#pragma unroll
        for (int i = 0; i < 2; i++) {
            int chunk = tid + i * 256;          // 512 chunks of 8 elems
            int row = chunk >> 2, c4 = chunk & 3;
            cvt8(X + (size_t)(m0 + row) * HID + k0 + c4 * 8, As + row * LDA + c4 * 8);
            cvt8(W + (size_t)(n0 + row) * HID + k0 + c4 * 8, Bs + row * LDA + c4 * 8);
        }
        __syncthreads();

        bf16x8 afr[4], bfr[4];
#pragma unroll
        for (int mb = 0; mb < 4; mb++)
            afr[mb] = *(const bf16x8*)(As + (wm * 64 + mb * 16 + l15) * LDA + quad * 8);
#pragma unroll
        for (int nb = 0; nb < 4; nb++)
            bfr[nb] = *(const bf16x8*)(Bs + (wn * 64 + nb * 16 + l15) * LDA + quad * 8);
#pragma unroll
        for (int mb = 0; mb < 4; mb++)
#pragma unroll
            for (int nb = 0; nb < 4; nb++)
                acc[mb][nb] = mfma16(afr[mb], bfr[nb], acc[mb][nb]);
    }

    // epilogue: scatter to q / k / vT workspaces (bf16)
#pragma unroll
    for (int nb = 0; nb < 4; nb++) {
        int n = n0 + wn * 64 + nb * 16 + l15;
        float bv = bias[n];
        int mat = n >> 11;        // 0=q,1=k,2=v
        int h   = (n >> 7) & 15;
        int d   = n & 127;
#pragma unroll
        for (int mb = 0; mb < 4; mb++) {
#pragma unroll
            for (int r = 0; r < 4; r++) {
                int m = m0 + wm * 64 + mb * 16 + quad * 4 + r;
                int b = m >> 11;
                int s = m & 2047;
                ushort_t val = f2bf(acc[mb][nb][r] + bv);
                if (mat == 0)
                    qws[(((size_t)(b * 16 + h) * SS) + s) * DHEAD + d] = val;
                else if (mat == 1)
                    kws[(((size_t)(b * 16 + h) * SS) + s) * DHEAD + d] = val;
                else
                    vtws[(((size_t)(b * 16 + h) * DHEAD) + d) * SS + s] = val;
            }
        }
    }
}

// ---------------------------------------------------------------------------
// Kernel 2: RoPE in-place on q and k ([B,H,S,Dh] bf16 layout).
// Thread per (b,h,s,d2), d2 in [0,64): handles the (d2, d2+64) pair.
// ---------------------------------------------------------------------------
__global__ void rope_kernel(ushort_t* __restrict__ qws, ushort_t* __restrict__ kws)
{
    int idx = blockIdx.x * blockDim.x + threadIdx.x;   // 2*16*2048*64 threads
    int d2 = idx & 63;
    int s  = (idx >> 6) & 2047;
    int bh = idx >> 17;

    float inv_freq = powf(10000.f, -(float)d2 * (1.f / 64.f));
    float fr = (float)s * inv_freq;
    float sn, cs;
    sincosf(fr, &sn, &cs);

    size_t base = ((size_t)bh * SS + s) * DHEAD;
    float q1 = bf2f(qws[base + d2]);
    float q2 = bf2f(qws[base + 64 + d2]);
    qws[base + d2]      = f2bf(q1 * cs - q2 * sn);
    qws[base + 64 + d2] = f2bf(q2 * cs + q1 * sn);
    float k1 = bf2f(kws[base + d2]);
    float k2 = bf2f(kws[base + 64 + d2]);
    kws[base + d2]      = f2bf(k1 * cs - k2 * sn);
    kws[base + 64 + d2] = f2bf(k2 * cs + k1 * sn);
}

// ---------------------------------------------------------------------------
// Kernel 3: causal flash attention.
// Block = (bh, q-tile of 64). 4 waves x 16 q-rows each. K-tiles of 64.
// q,k: [B,H,S,Dh]; vT: [B,H,Dh,S]; aout: [B*S][HID] bf16 (dense-GEMM A).
// ---------------------------------------------------------------------------
#define LDQK 136   // 128 + 8
#define LDVT 72    // 64 + 8
#define LDP  72
#define NEG_BIG (-1.0e30f)

__global__ __launch_bounds__(256, 2) void attn_kernel(
    const ushort_t* __restrict__ qws,
    const ushort_t* __restrict__ kws,
    const ushort_t* __restrict__ vtws,
    ushort_t* __restrict__ aout)
{
    __shared__ __align__(16) ushort_t q_s[64 * LDQK];
    __shared__ __align__(16) ushort_t k_s[64 * LDQK];
    __shared__ __align__(16) ushort_t vt_s[128 * LDVT];
    __shared__ __align__(16) ushort_t p_s[4][16 * LDP];

    const int tid  = threadIdx.x;
    const int lane = tid & 63;
    const int w    = tid >> 6;
    const int quad = lane >> 4;
    const int l15  = lane & 15;

    const int bh = blockIdx.y;              // b*16+h
    const int q0 = blockIdx.x * 64;
    const size_t qk_base = (size_t)bh * SS * DHEAD;

    // stage Q tile (64 x 128)
#pragma unroll
    for (int i = 0; i < 4; i++) {
        int chunk = tid + i * 256;          // 1024 chunks
        int row = chunk >> 4, c = chunk & 15;
        *(uint4*)(q_s + row * LDQK + c * 8) =
            *(const uint4*)(qws + qk_base + (size_t)(q0 + row) * DHEAD + c * 8);
    }

    float m_st[4], l_st[4];
    f32x4 o_acc[8];
    for (int r = 0; r < 4; r++) { m_st[r] = NEG_BIG; l_st[r] = 0.f; }
    for (int i = 0; i < 8; i++)
        for (int e = 0; e < 4; e++) o_acc[i][e] = 0.f;

    const float scale = 0.08838834764831845f;   // 1/sqrt(128)
    const int ntiles = q0 / 64 + 1;             // causal bound

    for (int t = 0; t < ntiles; t++) {
        const int kb = t * 64;
        __syncthreads();
#pragma unroll
        for (int i = 0; i < 4; i++) {
            int chunk = tid + i * 256;
            int row = chunk >> 4, c = chunk & 15;   // K: 64 rows x 16 chunks
            *(uint4*)(k_s + row * LDQK + c * 8) =
                *(const uint4*)(kws + qk_base + (size_t)(kb + row) * DHEAD + c * 8);
        }
#pragma unroll
        for (int i = 0; i < 4; i++) {
            int chunk = tid + i * 256;
            int row = chunk >> 3, c = chunk & 7;    // VT: 128 rows x 8 chunks
            *(uint4*)(vt_s + row * LDVT + c * 8) =
                *(const uint4*)(vtws + qk_base + (size_t)row * SS + kb + c * 8);
        }
        __syncthreads();

        // S = Q K^T  (16 q-rows x 64 k-cols per wave)
        f32x4 s_acc[4];
        for (int nb = 0; nb < 4; nb++)
            for (int e = 0; e < 4; e++) s_acc[nb][e] = 0.f;
#pragma unroll
        for (int kc = 0; kc < 4; kc++) {
            bf16x8 a = *(const bf16x8*)(q_s + (w * 16 + l15) * LDQK + kc * 32 + quad * 8);
#pragma unroll
            for (int nb = 0; nb < 4; nb++) {
                bf16x8 b = *(const bf16x8*)(k_s + (nb * 16 + l15) * LDQK + kc * 32 + quad * 8);
                s_acc[nb] = mfma16(a, b, s_acc[nb]);
            }
        }

        // scale + causal mask
        const int q_row_base = q0 + w * 16 + quad * 4;
        float sv[4][4];
        float tmax[4];
        for (int r = 0; r < 4; r++) tmax[r] = NEG_BIG;
#pragma unroll
        for (int nb = 0; nb < 4; nb++) {
            int kidx = kb + nb * 16 + l15;
#pragma unroll
            for (int r = 0; r < 4; r++) {
                float v = s_acc[nb][r] * scale;
                v = (kidx <= q_row_base + r) ? v : NEG_BIG;
                sv[nb][r] = v;
                tmax[r] = fmaxf(tmax[r], v);
            }
        }
        // row-max across the 16 lanes of each quad
#pragma unroll
        for (int r = 0; r < 4; r++) {
            float v = tmax[r];
            v = fmaxf(v, __shfl_xor(v, 1));
            v = fmaxf(v, __shfl_xor(v, 2));
            v = fmaxf(v, __shfl_xor(v, 4));
            v = fmaxf(v, __shfl_xor(v, 8));
            tmax[r] = v;
        }
        float alpha[4], rsum[4];
#pragma unroll
        for (int r = 0; r < 4; r++) {
            float mn = fmaxf(m_st[r], tmax[r]);
            alpha[r] = __expf(fmaxf(m_st[r] - mn, -80.f));
            m_st[r] = mn;
            rsum[r] = 0.f;
        }
        // P = exp(S - m), write to LDS (C-layout -> A-layout round trip)
#pragma unroll
        for (int nb = 0; nb < 4; nb++) {
#pragma unroll
            for (int r = 0; r < 4; r++) {
                float p = __expf(fmaxf(sv[nb][r] - m_st[r], -80.f));
                rsum[r] += p;
                p_s[w][(quad * 4 + r) * LDP + nb * 16 + l15] = f2bf(p);
            }
        }
#pragma unroll
        for (int r = 0; r < 4; r++) {
            float v = rsum[r];
            v += __shfl_xor(v, 1);
            v += __shfl_xor(v, 2);
            v += __shfl_xor(v, 4);
            v += __shfl_xor(v, 8);
            l_st[r] = l_st[r] * alpha[r] + v;
        }
        // rescale O
#pragma unroll
        for (int i = 0; i < 8; i++)
#pragma unroll
            for (int r = 0; r < 4; r++) o_acc[i][r] *= alpha[r];

        __syncthreads();   // uniform trip count; orders p_s/vt_s usage

        // O += P * V   (P: A-operand from LDS; vT rows give contiguous B-frags)
#pragma unroll
        for (int kc = 0; kc < 2; kc++) {
            bf16x8 p = *(const bf16x8*)(p_s[w] + l15 * LDP + kc * 32 + quad * 8);
#pragma unroll
            for (int db = 0; db < 8; db++) {
                bf16x8 vfr = *(const bf16x8*)(vt_s + (db * 16 + l15) * LDVT + kc * 32 + quad * 8);
                o_acc[db] = mfma16(p, vfr, o_acc[db]);
            }
        }
    }

    // write out: aout[b*S + s][h*128 + d]  (bf16)
    const int b = bh >> 4;
    const int h = bh & 15;
    float inv_l[4];
    for (int r = 0; r < 4; r++) inv_l[r] = 1.f / l_st[r];
#pragma unroll
    for (int db = 0; db < 8; db++) {
#pragma unroll
        for (int r = 0; r < 4; r++) {
            int srow = q0 + w * 16 + quad * 4 + r;
            size_t off = ((size_t)(b * SS + srow)) * HID + h * DHEAD + db * 16 + l15;
            aout[off] = f2bf(o_acc[db][r] * inv_l[r]);
        }
    }
}

// ---------------------------------------------------------------------------
// Kernel 4: dense GEMM. out[m][n] = sum_k A[m][k]*Wd[n][k] + bd[n]
// A: bf16 workspace; Wd, bd: f32 inputs; out: f32.
// ---------------------------------------------------------------------------
__global__ __launch_bounds__(256, 2) void dense_gemm_kernel(
    const ushort_t* __restrict__ A,
    const float* __restrict__ W,
    const float* __restrict__ bias,
    float* __restrict__ out)
{
    __shared__ __align__(16) ushort_t As[128 * LDA];
    __shared__ __align__(16) ushort_t Bs[128 * LDA];
    const int tid  = threadIdx.x;
    const int lane = tid & 63;
    const int w    = tid >> 6;
    const int wm   = w >> 1, wn = w & 1;
    const int quad = lane >> 4;
    const int l15  = lane & 15;
    const int m0 = blockIdx.y * 128;
    const int n0 = blockIdx.x * 128;

    f32x4 acc[4][4];
    for (int i = 0; i < 4; i++)
        for (int j = 0; j < 4; j++)
            for (int e = 0; e < 4; e++) acc[i][j][e] = 0.f;

    for (int k0 = 0; k0 < HID; k0 += 32) {
        __syncthreads();
#pragma unroll
        for (int i = 0; i < 2; i++) {
            int chunk = tid + i * 256;
            int row = chunk >> 2, c4 = chunk & 3;
            *(uint4*)(As + row * LDA + c4 * 8) =
                *(const uint4*)(A + (size_t)(m0 + row) * HID + k0 + c4 * 8);
            cvt8(W + (size_t)(n0 + row) * HID + k0 + c4 * 8, Bs + row * LDA + c4 * 8);
        }
        __syncthreads();

        bf16x8 afr[4], bfr[4];
#pragma unroll
        for (int mb = 0; mb < 4; mb++)
            afr[mb] = *(const bf16x8*)(As + (wm * 64 + mb * 16 + l15) * LDA + quad * 8);
#pragma unroll
        for (int nb = 0; nb < 4; nb++)
            bfr[nb] = *(const bf16x8*)(Bs + (wn * 64 + nb * 16 + l15) * LDA + quad * 8);
#pragma unroll
        for (int mb = 0; mb < 4; mb++)
#pragma unroll
            for (int nb = 0; nb < 4; nb++)
                acc[mb][nb] = mfma16(afr[mb], bfr[nb], acc[mb][nb]);
    }

#pragma unroll
    for (int nb = 0; nb < 4; nb++) {
        int n = n0 + wn * 64 + nb * 16 + l15;
        float bv = bias[n];
#pragma unroll
        for (int mb = 0; mb < 4; mb++) {
#pragma unroll
            for (int r = 0; r < 4; r++) {
                int m = m0 + wm * 64 + mb * 16 + quad * 4 + r;
                out[(size_t)m * HID + n] = acc[mb][nb][r] + bv;
            }
        }
    }
}

// ---------------------------------------------------------------------------
extern "C" void kernel_launch(void* const* d_in, const int* in_sizes, int n_in,
                              void* d_out, int out_size, void* d_ws, size_t ws_size,
                              hipStream_t stream)
{
    const float* X    = (const float*)d_in[0];
    const float* Wqkv = (const float*)d_in[1];
    const float* bqkv = (const float*)d_in[2];
    const float* Wd   = (const float*)d_in[3];
    const float* bd   = (const float*)d_in[4];
    float* out = (float*)d_out;

    char* ws = (char*)d_ws;
    ushort_t* qws  = (ushort_t*)(ws);                         // 16 MB [B,H,S,D] bf16
    ushort_t* kws  = (ushort_t*)(ws + (size_t)16 * 1048576);  // 16 MB [B,H,S,D] bf16
    ushort_t* vtws = (ushort_t*)(ws + (size_t)32 * 1048576);  // 16 MB [B,H,D,S] bf16
    ushort_t* aout = (ushort_t*)(ws + (size_t)48 * 1048576);  // 16 MB [B*S,HID] bf16

    qkv_gemm_kernel<<<dim3(NQKV / 128, MM / 128), 256, 0, stream>>>(X, Wqkv, bqkv, qws, kws, vtws);
    rope_kernel<<<(BB * NHEAD * SS * 64) / 256, 256, 0, stream>>>(qws, kws);
    attn_kernel<<<dim3(SS / 64, BB * NHEAD), 256, 0, stream>>>(qws, kws, vtws, aout);
    dense_gemm_kernel<<<dim3(HID / 128, MM / 128), 256, 0, stream>>>(aout, Wd, bd, out);
}

// Round 3
// 545.825 us; speedup vs baseline: 1.3551x; 1.3551x over previous
//
#include <hip/hip_runtime.h>
#include <hip/hip_bf16.h>
#include <stdint.h>

#define HID 2048
#define NHEAD 16
#define DHEAD 128
#define BB 2
#define SS 2048
#define MM (BB*SS)       // 4096
#define NQKV (3*HID)     // 6144

typedef __attribute__((ext_vector_type(8))) short bf16x8;
typedef __attribute__((ext_vector_type(4))) float f32x4;
typedef unsigned short ushort_t;

__device__ __forceinline__ f32x4 mfma16(bf16x8 a, bf16x8 b, f32x4 c) {
    return __builtin_amdgcn_mfma_f32_16x16x32_bf16(a, b, c, 0, 0, 0);
}

__device__ __forceinline__ float bf2f(ushort_t u) {
    unsigned int x = ((unsigned int)u) << 16;
    return __builtin_bit_cast(float, x);
}
__device__ __forceinline__ ushort_t f2bf(float f) {
    unsigned int x = __builtin_bit_cast(unsigned int, f);
    unsigned int r = (x + 0x7FFFu + ((x >> 16) & 1u)) >> 16;
    return (ushort_t)r;
}

// load 8 contiguous f32, round to bf16, store as one 16B chunk (generic ptr)
__device__ __forceinline__ void cvt8(const float* __restrict__ g, ushort_t* l) {
    float4 a = *(const float4*)g;
    float4 b = *(const float4*)(g + 4);
    union { ushort_t u[8]; uint4 v; } t;
    t.u[0] = f2bf(a.x); t.u[1] = f2bf(a.y); t.u[2] = f2bf(a.z); t.u[3] = f2bf(a.w);
    t.u[4] = f2bf(b.x); t.u[5] = f2bf(b.y); t.u[6] = f2bf(b.z); t.u[7] = f2bf(b.w);
    *(uint4*)l = t.v;
}

// async global->LDS, 16 bytes per lane; LDS base must be wave-uniform
__device__ __forceinline__ void gload16(const ushort_t* g, ushort_t* l) {
    __builtin_amdgcn_global_load_lds(
        (const __attribute__((address_space(1))) unsigned int*)(const void*)g,
        (__attribute__((address_space(3))) unsigned int*)(void*)l,
        16, 0, 0);
}

// ---------------------------------------------------------------------------
// f32 -> bf16 bulk convert (memory-bound pre-pass)
// ---------------------------------------------------------------------------
__global__ void cvt_kernel(const float* __restrict__ src, ushort_t* __restrict__ dst, int n8)
{
    int i = blockIdx.x * blockDim.x + threadIdx.x;
    if (i < n8) cvt8(src + (size_t)i * 8, dst + (size_t)i * 8);
}

// ---------------------------------------------------------------------------
// FAST QKV GEMM (m97 structure): bf16 inputs via global_load_lds width=16,
// unpadded 128x32 LDS tiles. C[m][n] = sum_k X[m][k]*W[n][k] + bias[n].
// Epilogue scatters bf16: n in [0,2048)->q; [2048,4096)->k; [4096,6144)->vT.
// ---------------------------------------------------------------------------
__global__ __launch_bounds__(256, 2) void qkv_gemm_fast(
    const ushort_t* __restrict__ X,
    const ushort_t* __restrict__ W,
    const float* __restrict__ bias,
    ushort_t* __restrict__ qws,
    ushort_t* __restrict__ kws,
    ushort_t* __restrict__ vtws)
{
    __shared__ __align__(16) ushort_t As[128 * 32];
    __shared__ __align__(16) ushort_t Bs[128 * 32];
    const int tid  = threadIdx.x;
    const int lane = tid & 63;
    const int w    = tid >> 6;
    const int wm   = w >> 1, wn = w & 1;
    const int quad = lane >> 4;
    const int l15  = lane & 15;
    const int m0 = blockIdx.y * 128;
    const int n0 = blockIdx.x * 128;

    f32x4 acc[4][4];
    for (int i = 0; i < 4; i++)
        for (int j = 0; j < 4; j++)
            for (int e = 0; e < 4; e++) acc[i][j][e] = 0.f;

    for (int k0 = 0; k0 < HID; k0 += 32) {
        __syncthreads();
#pragma unroll
        for (int i = 0; i < 2; i++) {
            int cbase = i * 256 + w * 64;       // wave-uniform chunk base
            int c = cbase + lane;               // this lane's 16B chunk
            int row = c >> 2, cc = c & 3;
            gload16(X + (size_t)(m0 + row) * HID + k0 + cc * 8, As + cbase * 8);
            gload16(W + (size_t)(n0 + row) * HID + k0 + cc * 8, Bs + cbase * 8);
        }
        __syncthreads();

        bf16x8 afr[4], bfr[4];
#pragma unroll
        for (int mb = 0; mb < 4; mb++)
            afr[mb] = *(const bf16x8*)(As + (wm * 64 + mb * 16 + l15) * 32 + quad * 8);
#pragma unroll
        for (int nb = 0; nb < 4; nb++)
            bfr[nb] = *(const bf16x8*)(Bs + (wn * 64 + nb * 16 + l15) * 32 + quad * 8);
#pragma unroll
        for (int mb = 0; mb < 4; mb++)
#pragma unroll
            for (int nb = 0; nb < 4; nb++)
                acc[mb][nb] = mfma16(afr[mb], bfr[nb], acc[mb][nb]);
    }

#pragma unroll
    for (int nb = 0; nb < 4; nb++) {
        int n = n0 + wn * 64 + nb * 16 + l15;
        float bv = bias[n];
        int mat = n >> 11;        // 0=q,1=k,2=v
        int h   = (n >> 7) & 15;
        int d   = n & 127;
#pragma unroll
        for (int mb = 0; mb < 4; mb++) {
#pragma unroll
            for (int r = 0; r < 4; r++) {
                int m = m0 + wm * 64 + mb * 16 + quad * 4 + r;
                int b = m >> 11;
                int s = m & 2047;
                ushort_t val = f2bf(acc[mb][nb][r] + bv);
                if (mat == 0)
                    qws[(((size_t)(b * 16 + h) * SS) + s) * DHEAD + d] = val;
                else if (mat == 1)
                    kws[(((size_t)(b * 16 + h) * SS) + s) * DHEAD + d] = val;
                else
                    vtws[(((size_t)(b * 16 + h) * DHEAD) + d) * SS + s] = val;
            }
        }
    }
}

// ---------------------------------------------------------------------------
// FAST dense GEMM (m97 structure). A bf16 ws, W bf16 ws, out f32.
// ---------------------------------------------------------------------------
__global__ __launch_bounds__(256, 2) void dense_gemm_fast(
    const ushort_t* __restrict__ A,
    const ushort_t* __restrict__ W,
    const float* __restrict__ bias,
    float* __restrict__ out)
{
    __shared__ __align__(16) ushort_t As[128 * 32];
    __shared__ __align__(16) ushort_t Bs[128 * 32];
    const int tid  = threadIdx.x;
    const int lane = tid & 63;
    const int w    = tid >> 6;
    const int wm   = w >> 1, wn = w & 1;
    const int quad = lane >> 4;
    const int l15  = lane & 15;
    const int m0 = blockIdx.y * 128;
    const int n0 = blockIdx.x * 128;

    f32x4 acc[4][4];
    for (int i = 0; i < 4; i++)
        for (int j = 0; j < 4; j++)
            for (int e = 0; e < 4; e++) acc[i][j][e] = 0.f;

    for (int k0 = 0; k0 < HID; k0 += 32) {
        __syncthreads();
#pragma unroll
        for (int i = 0; i < 2; i++) {
            int cbase = i * 256 + w * 64;
            int c = cbase + lane;
            int row = c >> 2, cc = c & 3;
            gload16(A + (size_t)(m0 + row) * HID + k0 + cc * 8, As + cbase * 8);
            gload16(W + (size_t)(n0 + row) * HID + k0 + cc * 8, Bs + cbase * 8);
        }
        __syncthreads();

        bf16x8 afr[4], bfr[4];
#pragma unroll
        for (int mb = 0; mb < 4; mb++)
            afr[mb] = *(const bf16x8*)(As + (wm * 64 + mb * 16 + l15) * 32 + quad * 8);
#pragma unroll
        for (int nb = 0; nb < 4; nb++)
            bfr[nb] = *(const bf16x8*)(Bs + (wn * 64 + nb * 16 + l15) * 32 + quad * 8);
#pragma unroll
        for (int mb = 0; mb < 4; mb++)
#pragma unroll
            for (int nb = 0; nb < 4; nb++)
                acc[mb][nb] = mfma16(afr[mb], bfr[nb], acc[mb][nb]);
    }

#pragma unroll
    for (int nb = 0; nb < 4; nb++) {
        int n = n0 + wn * 64 + nb * 16 + l15;
        float bv = bias[n];
#pragma unroll
        for (int mb = 0; mb < 4; mb++) {
#pragma unroll
            for (int r = 0; r < 4; r++) {
                int m = m0 + wm * 64 + mb * 16 + quad * 4 + r;
                out[(size_t)m * HID + n] = acc[mb][nb][r] + bv;
            }
        }
    }
}

// ---------------------------------------------------------------------------
// FALLBACK kernels (round-2 versions; used when ws_size < 96 MiB)
// ---------------------------------------------------------------------------
#define LDA 40   // 32 + 8 pad

__global__ __launch_bounds__(256, 2) void qkv_gemm_kernel(
    const float* __restrict__ X,
    const float* __restrict__ W,
    const float* __restrict__ bias,
    ushort_t* __restrict__ qws,
    ushort_t* __restrict__ kws,
    ushort_t* __restrict__ vtws)
{
    __shared__ __align__(16) ushort_t As[128 * LDA];
    __shared__ __align__(16) ushort_t Bs[128 * LDA];
    const int tid  = threadIdx.x;
    const int lane = tid & 63;
    const int w    = tid >> 6;
    const int wm   = w >> 1, wn = w & 1;
    const int quad = lane >> 4;
    const int l15  = lane & 15;
    const int m0 = blockIdx.y * 128;
    const int n0 = blockIdx.x * 128;

    f32x4 acc[4][4];
    for (int i = 0; i < 4; i++)
        for (int j = 0; j < 4; j++)
            for (int e = 0; e < 4; e++) acc[i][j][e] = 0.f;

    for (int k0 = 0; k0 < HID; k0 += 32) {
        __syncthreads();
#pragma unroll
        for (int i = 0; i < 2; i++) {
            int chunk = tid + i * 256;
            int row = chunk >> 2, c4 = chunk & 3;
            cvt8(X + (size_t)(m0 + row) * HID + k0 + c4 * 8, As + row * LDA + c4 * 8);
            cvt8(W + (size_t)(n0 + row) * HID + k0 + c4 * 8, Bs + row * LDA + c4 * 8);
        }
        __syncthreads();

        bf16x8 afr[4], bfr[4];
#pragma unroll
        for (int mb = 0; mb < 4; mb++)
            afr[mb] = *(const bf16x8*)(As + (wm * 64 + mb * 16 + l15) * LDA + quad * 8);
#pragma unroll
        for (int nb = 0; nb < 4; nb++)
            bfr[nb] = *(const bf16x8*)(Bs + (wn * 64 + nb * 16 + l15) * LDA + quad * 8);
#pragma unroll
        for (int mb = 0; mb < 4; mb++)
#pragma unroll
            for (int nb = 0; nb < 4; nb++)
                acc[mb][nb] = mfma16(afr[mb], bfr[nb], acc[mb][nb]);
    }

#pragma unroll
    for (int nb = 0; nb < 4; nb++) {
        int n = n0 + wn * 64 + nb * 16 + l15;
        float bv = bias[n];
        int mat = n >> 11;
        int h   = (n >> 7) & 15;
        int d   = n & 127;
#pragma unroll
        for (int mb = 0; mb < 4; mb++) {
#pragma unroll
            for (int r = 0; r < 4; r++) {
                int m = m0 + wm * 64 + mb * 16 + quad * 4 + r;
                int b = m >> 11;
                int s = m & 2047;
                ushort_t val = f2bf(acc[mb][nb][r] + bv);
                if (mat == 0)
                    qws[(((size_t)(b * 16 + h) * SS) + s) * DHEAD + d] = val;
                else if (mat == 1)
                    kws[(((size_t)(b * 16 + h) * SS) + s) * DHEAD + d] = val;
                else
                    vtws[(((size_t)(b * 16 + h) * DHEAD) + d) * SS + s] = val;
            }
        }
    }
}

__global__ __launch_bounds__(256, 2) void dense_gemm_kernel(
    const ushort_t* __restrict__ A,
    const float* __restrict__ W,
    const float* __restrict__ bias,
    float* __restrict__ out)
{
    __shared__ __align__(16) ushort_t As[128 * LDA];
    __shared__ __align__(16) ushort_t Bs[128 * LDA];
    const int tid  = threadIdx.x;
    const int lane = tid & 63;
    const int w    = tid >> 6;
    const int wm   = w >> 1, wn = w & 1;
    const int quad = lane >> 4;
    const int l15  = lane & 15;
    const int m0 = blockIdx.y * 128;
    const int n0 = blockIdx.x * 128;

    f32x4 acc[4][4];
    for (int i = 0; i < 4; i++)
        for (int j = 0; j < 4; j++)
            for (int e = 0; e < 4; e++) acc[i][j][e] = 0.f;

    for (int k0 = 0; k0 < HID; k0 += 32) {
        __syncthreads();
#pragma unroll
        for (int i = 0; i < 2; i++) {
            int chunk = tid + i * 256;
            int row = chunk >> 2, c4 = chunk & 3;
            *(uint4*)(As + row * LDA + c4 * 8) =
                *(const uint4*)(A + (size_t)(m0 + row) * HID + k0 + c4 * 8);
            cvt8(W + (size_t)(n0 + row) * HID + k0 + c4 * 8, Bs + row * LDA + c4 * 8);
        }
        __syncthreads();

        bf16x8 afr[4], bfr[4];
#pragma unroll
        for (int mb = 0; mb < 4; mb++)
            afr[mb] = *(const bf16x8*)(As + (wm * 64 + mb * 16 + l15) * LDA + quad * 8);
#pragma unroll
        for (int nb = 0; nb < 4; nb++)
            bfr[nb] = *(const bf16x8*)(Bs + (wn * 64 + nb * 16 + l15) * LDA + quad * 8);
#pragma unroll
        for (int mb = 0; mb < 4; mb++)
#pragma unroll
            for (int nb = 0; nb < 4; nb++)
                acc[mb][nb] = mfma16(afr[mb], bfr[nb], acc[mb][nb]);
    }

#pragma unroll
    for (int nb = 0; nb < 4; nb++) {
        int n = n0 + wn * 64 + nb * 16 + l15;
        float bv = bias[n];
#pragma unroll
        for (int mb = 0; mb < 4; mb++) {
#pragma unroll
            for (int r = 0; r < 4; r++) {
                int m = m0 + wm * 64 + mb * 16 + quad * 4 + r;
                out[(size_t)m * HID + n] = acc[mb][nb][r] + bv;
            }
        }
    }
}

// ---------------------------------------------------------------------------
// RoPE in-place on q and k ([B,H,S,Dh] bf16 layout).
// ---------------------------------------------------------------------------
__global__ void rope_kernel(ushort_t* __restrict__ qws, ushort_t* __restrict__ kws)
{
    int idx = blockIdx.x * blockDim.x + threadIdx.x;
    int d2 = idx & 63;
    int s  = (idx >> 6) & 2047;
    int bh = idx >> 17;

    float inv_freq = powf(10000.f, -(float)d2 * (1.f / 64.f));
    float fr = (float)s * inv_freq;
    float sn, cs;
    sincosf(fr, &sn, &cs);

    size_t base = ((size_t)bh * SS + s) * DHEAD;
    float q1 = bf2f(qws[base + d2]);
    float q2 = bf2f(qws[base + 64 + d2]);
    qws[base + d2]      = f2bf(q1 * cs - q2 * sn);
    qws[base + 64 + d2] = f2bf(q2 * cs + q1 * sn);
    float k1 = bf2f(kws[base + d2]);
    float k2 = bf2f(kws[base + 64 + d2]);
    kws[base + d2]      = f2bf(k1 * cs - k2 * sn);
    kws[base + 64 + d2] = f2bf(k2 * cs + k1 * sn);
}

// ---------------------------------------------------------------------------
// Causal flash attention (unchanged from round 2).
// ---------------------------------------------------------------------------
#define LDQK 136
#define LDVT 72
#define LDP  72
#define NEG_BIG (-1.0e30f)

__global__ __launch_bounds__(256, 2) void attn_kernel(
    const ushort_t* __restrict__ qws,
    const ushort_t* __restrict__ kws,
    const ushort_t* __restrict__ vtws,
    ushort_t* __restrict__ aout)
{
    __shared__ __align__(16) ushort_t q_s[64 * LDQK];
    __shared__ __align__(16) ushort_t k_s[64 * LDQK];
    __shared__ __align__(16) ushort_t vt_s[128 * LDVT];
    __shared__ __align__(16) ushort_t p_s[4][16 * LDP];

    const int tid  = threadIdx.x;
    const int lane = tid & 63;
    const int w    = tid >> 6;
    const int quad = lane >> 4;
    const int l15  = lane & 15;

    const int bh = blockIdx.y;
    const int q0 = blockIdx.x * 64;
    const size_t qk_base = (size_t)bh * SS * DHEAD;

#pragma unroll
    for (int i = 0; i < 4; i++) {
        int chunk = tid + i * 256;
        int row = chunk >> 4, c = chunk & 15;
        *(uint4*)(q_s + row * LDQK + c * 8) =
            *(const uint4*)(qws + qk_base + (size_t)(q0 + row) * DHEAD + c * 8);
    }

    float m_st[4], l_st[4];
    f32x4 o_acc[8];
    for (int r = 0; r < 4; r++) { m_st[r] = NEG_BIG; l_st[r] = 0.f; }
    for (int i = 0; i < 8; i++)
        for (int e = 0; e < 4; e++) o_acc[i][e] = 0.f;

    const float scale = 0.08838834764831845f;
    const int ntiles = q0 / 64 + 1;

    for (int t = 0; t < ntiles; t++) {
        const int kb = t * 64;
        __syncthreads();
#pragma unroll
        for (int i = 0; i < 4; i++) {
            int chunk = tid + i * 256;
            int row = chunk >> 4, c = chunk & 15;
            *(uint4*)(k_s + row * LDQK + c * 8) =
                *(const uint4*)(kws + qk_base + (size_t)(kb + row) * DHEAD + c * 8);
        }
#pragma unroll
        for (int i = 0; i < 4; i++) {
            int chunk = tid + i * 256;
            int row = chunk >> 3, c = chunk & 7;
            *(uint4*)(vt_s + row * LDVT + c * 8) =
                *(const uint4*)(vtws + qk_base + (size_t)row * SS + kb + c * 8);
        }
        __syncthreads();

        f32x4 s_acc[4];
        for (int nb = 0; nb < 4; nb++)
            for (int e = 0; e < 4; e++) s_acc[nb][e] = 0.f;
#pragma unroll
        for (int kc = 0; kc < 4; kc++) {
            bf16x8 a = *(const bf16x8*)(q_s + (w * 16 + l15) * LDQK + kc * 32 + quad * 8);
#pragma unroll
            for (int nb = 0; nb < 4; nb++) {
                bf16x8 b = *(const bf16x8*)(k_s + (nb * 16 + l15) * LDQK + kc * 32 + quad * 8);
                s_acc[nb] = mfma16(a, b, s_acc[nb]);
            }
        }

        const int q_row_base = q0 + w * 16 + quad * 4;
        float sv[4][4];
        float tmax[4];
        for (int r = 0; r < 4; r++) tmax[r] = NEG_BIG;
#pragma unroll
        for (int nb = 0; nb < 4; nb++) {
            int kidx = kb + nb * 16 + l15;
#pragma unroll
            for (int r = 0; r < 4; r++) {
                float v = s_acc[nb][r] * scale;
                v = (kidx <= q_row_base + r) ? v : NEG_BIG;
                sv[nb][r] = v;
                tmax[r] = fmaxf(tmax[r], v);
            }
        }
#pragma unroll
        for (int r = 0; r < 4; r++) {
            float v = tmax[r];
            v = fmaxf(v, __shfl_xor(v, 1));
            v = fmaxf(v, __shfl_xor(v, 2));
            v = fmaxf(v, __shfl_xor(v, 4));
            v = fmaxf(v, __shfl_xor(v, 8));
            tmax[r] = v;
        }
        float alpha[4], rsum[4];
#pragma unroll
        for (int r = 0; r < 4; r++) {
            float mn = fmaxf(m_st[r], tmax[r]);
            alpha[r] = __expf(fmaxf(m_st[r] - mn, -80.f));
            m_st[r] = mn;
            rsum[r] = 0.f;
        }
#pragma unroll
        for (int nb = 0; nb < 4; nb++) {
#pragma unroll
            for (int r = 0; r < 4; r++) {
                float p = __expf(fmaxf(sv[nb][r] - m_st[r], -80.f));
                rsum[r] += p;
                p_s[w][(quad * 4 + r) * LDP + nb * 16 + l15] = f2bf(p);
            }
        }
#pragma unroll
        for (int r = 0; r < 4; r++) {
            float v = rsum[r];
            v += __shfl_xor(v, 1);
            v += __shfl_xor(v, 2);
            v += __shfl_xor(v, 4);
            v += __shfl_xor(v, 8);
            l_st[r] = l_st[r] * alpha[r] + v;
        }
#pragma unroll
        for (int i = 0; i < 8; i++)
#pragma unroll
            for (int r = 0; r < 4; r++) o_acc[i][r] *= alpha[r];

        __syncthreads();

#pragma unroll
        for (int kc = 0; kc < 2; kc++) {
            bf16x8 p = *(const bf16x8*)(p_s[w] + l15 * LDP + kc * 32 + quad * 8);
#pragma unroll
            for (int db = 0; db < 8; db++) {
                bf16x8 vfr = *(const bf16x8*)(vt_s + (db * 16 + l15) * LDVT + kc * 32 + quad * 8);
                o_acc[db] = mfma16(p, vfr, o_acc[db]);
            }
        }
    }

    const int b = bh >> 4;
    const int h = bh & 15;
    float inv_l[4];
    for (int r = 0; r < 4; r++) inv_l[r] = 1.f / l_st[r];
#pragma unroll
    for (int db = 0; db < 8; db++) {
#pragma unroll
        for (int r = 0; r < 4; r++) {
            int srow = q0 + w * 16 + quad * 4 + r;
            size_t off = ((size_t)(b * SS + srow)) * HID + h * DHEAD + db * 16 + l15;
            aout[off] = f2bf(o_acc[db][r] * inv_l[r]);
        }
    }
}

// ---------------------------------------------------------------------------
extern "C" void kernel_launch(void* const* d_in, const int* in_sizes, int n_in,
                              void* d_out, int out_size, void* d_ws, size_t ws_size,
                              hipStream_t stream)
{
    const float* X    = (const float*)d_in[0];
    const float* Wqkv = (const float*)d_in[1];
    const float* bqkv = (const float*)d_in[2];
    const float* Wd   = (const float*)d_in[3];
    const float* bd   = (const float*)d_in[4];
    float* out = (float*)d_out;

    char* ws = (char*)d_ws;
    const size_t MB = 1048576;
    ushort_t* qws  = (ushort_t*)(ws);              // 16 MiB [B,H,S,D] bf16
    ushort_t* kws  = (ushort_t*)(ws + 16 * MB);    // 16 MiB
    ushort_t* vtws = (ushort_t*)(ws + 32 * MB);    // 16 MiB [B,H,D,S]
    ushort_t* aout = (ushort_t*)(ws + 48 * MB);    // 16 MiB [B*S,HID] (aliases Xbf)

    if (ws_size >= 96 * MB) {
        ushort_t* Xbf  = (ushort_t*)(ws + 48 * MB);   // 16 MiB (dead after qkv; aout reuses)
        ushort_t* Wqbf = (ushort_t*)(ws + 64 * MB);   // 24 MiB
        ushort_t* Wdbf = (ushort_t*)(ws + 88 * MB);   // 8 MiB

        cvt_kernel<<<(MM * HID / 8 + 255) / 256, 256, 0, stream>>>(X, Xbf, MM * HID / 8);
        cvt_kernel<<<(NQKV * HID / 8 + 255) / 256, 256, 0, stream>>>(Wqkv, Wqbf, NQKV * HID / 8);
        cvt_kernel<<<(HID * HID / 8 + 255) / 256, 256, 0, stream>>>(Wd, Wdbf, HID * HID / 8);

        qkv_gemm_fast<<<dim3(NQKV / 128, MM / 128), 256, 0, stream>>>(Xbf, Wqbf, bqkv, qws, kws, vtws);
        rope_kernel<<<(BB * NHEAD * SS * 64) / 256, 256, 0, stream>>>(qws, kws);
        attn_kernel<<<dim3(SS / 64, BB * NHEAD), 256, 0, stream>>>(qws, kws, vtws, aout);
        dense_gemm_fast<<<dim3(HID / 128, MM / 128), 256, 0, stream>>>(aout, Wdbf, bd, out);
    } else {
        qkv_gemm_kernel<<<dim3(NQKV / 128, MM / 128), 256, 0, stream>>>(X, Wqkv, bqkv, qws, kws, vtws);
        rope_kernel<<<(BB * NHEAD * SS * 64) / 256, 256, 0, stream>>>(qws, kws);
        attn_kernel<<<dim3(SS / 64, BB * NHEAD), 256, 0, stream>>>(qws, kws, vtws, aout);
        dense_gemm_kernel<<<dim3(HID / 128, MM / 128), 256, 0, stream>>>(aout, Wd, bd, out);
    }
}

// Round 4
// 461.124 us; speedup vs baseline: 1.6041x; 1.1837x over previous
//
#include <hip/hip_runtime.h>
#include <hip/hip_bf16.h>
#include <stdint.h>

#define HID 2048
#define NHEAD 16
#define DHEAD 128
#define BB 2
#define SS 2048
#define MM (BB*SS)       // 4096
#define NQKV (3*HID)     // 6144
#define NT (SS/64)       // 32 k-tiles / q-tiles per head

typedef __attribute__((ext_vector_type(8))) short bf16x8;
typedef __attribute__((ext_vector_type(4))) float f32x4;
typedef unsigned short ushort_t;

__device__ __forceinline__ f32x4 mfma16(bf16x8 a, bf16x8 b, f32x4 c) {
    return __builtin_amdgcn_mfma_f32_16x16x32_bf16(a, b, c, 0, 0, 0);
}

__device__ __forceinline__ float bf2f(ushort_t u) {
    unsigned int x = ((unsigned int)u) << 16;
    return __builtin_bit_cast(float, x);
}
__device__ __forceinline__ ushort_t f2bf(float f) {
    unsigned int x = __builtin_bit_cast(unsigned int, f);
    unsigned int r = (x + 0x7FFFu + ((x >> 16) & 1u)) >> 16;
    return (ushort_t)r;
}

__device__ __forceinline__ void cvt8(const float* __restrict__ g, ushort_t* l) {
    float4 a = *(const float4*)g;
    float4 b = *(const float4*)(g + 4);
    union { ushort_t u[8]; uint4 v; } t;
    t.u[0] = f2bf(a.x); t.u[1] = f2bf(a.y); t.u[2] = f2bf(a.z); t.u[3] = f2bf(a.w);
    t.u[4] = f2bf(b.x); t.u[5] = f2bf(b.y); t.u[6] = f2bf(b.z); t.u[7] = f2bf(b.w);
    *(uint4*)l = t.v;
}

// async global->LDS, 16 bytes per lane; LDS base wave-uniform, HW adds lane*16
__device__ __forceinline__ void gload16(const ushort_t* g, ushort_t* l) {
    __builtin_amdgcn_global_load_lds(
        (const __attribute__((address_space(1))) unsigned int*)(const void*)g,
        (__attribute__((address_space(3))) unsigned int*)(void*)l,
        16, 0, 0);
}

// ---------------------------------------------------------------------------
// f32 -> bf16 bulk convert
// ---------------------------------------------------------------------------
__global__ void cvt_kernel(const float* __restrict__ src, ushort_t* __restrict__ dst, int n8)
{
    int i = blockIdx.x * blockDim.x + threadIdx.x;
    if (i < n8) cvt8(src + (size_t)i * 8, dst + (size_t)i * 8);
}

// ---------------------------------------------------------------------------
// FAST QKV GEMM (m97 structure, unchanged from round 3)
// ---------------------------------------------------------------------------
__global__ __launch_bounds__(256, 2) void qkv_gemm_fast(
    const ushort_t* __restrict__ X,
    const ushort_t* __restrict__ W,
    const float* __restrict__ bias,
    ushort_t* __restrict__ qws,
    ushort_t* __restrict__ kws,
    ushort_t* __restrict__ vtws)
{
    __shared__ __align__(16) ushort_t As[128 * 32];
    __shared__ __align__(16) ushort_t Bs[128 * 32];
    const int tid  = threadIdx.x;
    const int lane = tid & 63;
    const int w    = tid >> 6;
    const int wm   = w >> 1, wn = w & 1;
    const int quad = lane >> 4;
    const int l15  = lane & 15;
    const int m0 = blockIdx.y * 128;
    const int n0 = blockIdx.x * 128;

    f32x4 acc[4][4];
    for (int i = 0; i < 4; i++)
        for (int j = 0; j < 4; j++)
            for (int e = 0; e < 4; e++) acc[i][j][e] = 0.f;

    for (int k0 = 0; k0 < HID; k0 += 32) {
        __syncthreads();
#pragma unroll
        for (int i = 0; i < 2; i++) {
            int cbase = i * 256 + w * 64;
            int c = cbase + lane;
            int row = c >> 2, cc = c & 3;
            gload16(X + (size_t)(m0 + row) * HID + k0 + cc * 8, As + cbase * 8);
            gload16(W + (size_t)(n0 + row) * HID + k0 + cc * 8, Bs + cbase * 8);
        }
        __syncthreads();

        bf16x8 afr[4], bfr[4];
#pragma unroll
        for (int mb = 0; mb < 4; mb++)
            afr[mb] = *(const bf16x8*)(As + (wm * 64 + mb * 16 + l15) * 32 + quad * 8);
#pragma unroll
        for (int nb = 0; nb < 4; nb++)
            bfr[nb] = *(const bf16x8*)(Bs + (wn * 64 + nb * 16 + l15) * 32 + quad * 8);
#pragma unroll
        for (int mb = 0; mb < 4; mb++)
#pragma unroll
            for (int nb = 0; nb < 4; nb++)
                acc[mb][nb] = mfma16(afr[mb], bfr[nb], acc[mb][nb]);
    }

#pragma unroll
    for (int nb = 0; nb < 4; nb++) {
        int n = n0 + wn * 64 + nb * 16 + l15;
        float bv = bias[n];
        int mat = n >> 11;        // 0=q,1=k,2=v
        int h   = (n >> 7) & 15;
        int d   = n & 127;
#pragma unroll
        for (int mb = 0; mb < 4; mb++) {
#pragma unroll
            for (int r = 0; r < 4; r++) {
                int m = m0 + wm * 64 + mb * 16 + quad * 4 + r;
                int b = m >> 11;
                int s = m & 2047;
                ushort_t val = f2bf(acc[mb][nb][r] + bv);
                if (mat == 0)
                    qws[(((size_t)(b * 16 + h) * SS) + s) * DHEAD + d] = val;
                else if (mat == 1)
                    kws[(((size_t)(b * 16 + h) * SS) + s) * DHEAD + d] = val;
                else
                    vtws[(((size_t)(b * 16 + h) * DHEAD) + d) * SS + s] = val;
            }
        }
    }
}

// ---------------------------------------------------------------------------
// FAST dense GEMM (unchanged from round 3)
// ---------------------------------------------------------------------------
__global__ __launch_bounds__(256, 2) void dense_gemm_fast(
    const ushort_t* __restrict__ A,
    const ushort_t* __restrict__ W,
    const float* __restrict__ bias,
    float* __restrict__ out)
{
    __shared__ __align__(16) ushort_t As[128 * 32];
    __shared__ __align__(16) ushort_t Bs[128 * 32];
    const int tid  = threadIdx.x;
    const int lane = tid & 63;
    const int w    = tid >> 6;
    const int wm   = w >> 1, wn = w & 1;
    const int quad = lane >> 4;
    const int l15  = lane & 15;
    const int m0 = blockIdx.y * 128;
    const int n0 = blockIdx.x * 128;

    f32x4 acc[4][4];
    for (int i = 0; i < 4; i++)
        for (int j = 0; j < 4; j++)
            for (int e = 0; e < 4; e++) acc[i][j][e] = 0.f;

    for (int k0 = 0; k0 < HID; k0 += 32) {
        __syncthreads();
#pragma unroll
        for (int i = 0; i < 2; i++) {
            int cbase = i * 256 + w * 64;
            int c = cbase + lane;
            int row = c >> 2, cc = c & 3;
            gload16(A + (size_t)(m0 + row) * HID + k0 + cc * 8, As + cbase * 8);
            gload16(W + (size_t)(n0 + row) * HID + k0 + cc * 8, Bs + cbase * 8);
        }
        __syncthreads();

        bf16x8 afr[4], bfr[4];
#pragma unroll
        for (int mb = 0; mb < 4; mb++)
            afr[mb] = *(const bf16x8*)(As + (wm * 64 + mb * 16 + l15) * 32 + quad * 8);
#pragma unroll
        for (int nb = 0; nb < 4; nb++)
            bfr[nb] = *(const bf16x8*)(Bs + (wn * 64 + nb * 16 + l15) * 32 + quad * 8);
#pragma unroll
        for (int mb = 0; mb < 4; mb++)
#pragma unroll
            for (int nb = 0; nb < 4; nb++)
                acc[mb][nb] = mfma16(afr[mb], bfr[nb], acc[mb][nb]);
    }

#pragma unroll
    for (int nb = 0; nb < 4; nb++) {
        int n = n0 + wn * 64 + nb * 16 + l15;
        float bv = bias[n];
#pragma unroll
        for (int mb = 0; mb < 4; mb++) {
#pragma unroll
            for (int r = 0; r < 4; r++) {
                int m = m0 + wm * 64 + mb * 16 + quad * 4 + r;
                out[(size_t)m * HID + n] = acc[mb][nb][r] + bv;
            }
        }
    }
}

// ---------------------------------------------------------------------------
// FALLBACK GEMMs (round-2 style; used when ws_size < 96 MiB)
// ---------------------------------------------------------------------------
#define LDA 40

__global__ __launch_bounds__(256, 2) void qkv_gemm_kernel(
    const float* __restrict__ X,
    const float* __restrict__ W,
    const float* __restrict__ bias,
    ushort_t* __restrict__ qws,
    ushort_t* __restrict__ kws,
    ushort_t* __restrict__ vtws)
{
    __shared__ __align__(16) ushort_t As[128 * LDA];
    __shared__ __align__(16) ushort_t Bs[128 * LDA];
    const int tid  = threadIdx.x;
    const int lane = tid & 63;
    const int w    = tid >> 6;
    const int wm   = w >> 1, wn = w & 1;
    const int quad = lane >> 4;
    const int l15  = lane & 15;
    const int m0 = blockIdx.y * 128;
    const int n0 = blockIdx.x * 128;

    f32x4 acc[4][4];
    for (int i = 0; i < 4; i++)
        for (int j = 0; j < 4; j++)
            for (int e = 0; e < 4; e++) acc[i][j][e] = 0.f;

    for (int k0 = 0; k0 < HID; k0 += 32) {
        __syncthreads();
#pragma unroll
        for (int i = 0; i < 2; i++) {
            int chunk = tid + i * 256;
            int row = chunk >> 2, c4 = chunk & 3;
            cvt8(X + (size_t)(m0 + row) * HID + k0 + c4 * 8, As + row * LDA + c4 * 8);
            cvt8(W + (size_t)(n0 + row) * HID + k0 + c4 * 8, Bs + row * LDA + c4 * 8);
        }
        __syncthreads();

        bf16x8 afr[4], bfr[4];
#pragma unroll
        for (int mb = 0; mb < 4; mb++)
            afr[mb] = *(const bf16x8*)(As + (wm * 64 + mb * 16 + l15) * LDA + quad * 8);
#pragma unroll
        for (int nb = 0; nb < 4; nb++)
            bfr[nb] = *(const bf16x8*)(Bs + (wn * 64 + nb * 16 + l15) * LDA + quad * 8);
#pragma unroll
        for (int mb = 0; mb < 4; mb++)
#pragma unroll
            for (int nb = 0; nb < 4; nb++)
                acc[mb][nb] = mfma16(afr[mb], bfr[nb], acc[mb][nb]);
    }

#pragma unroll
    for (int nb = 0; nb < 4; nb++) {
        int n = n0 + wn * 64 + nb * 16 + l15;
        float bv = bias[n];
        int mat = n >> 11;
        int h   = (n >> 7) & 15;
        int d   = n & 127;
#pragma unroll
        for (int mb = 0; mb < 4; mb++) {
#pragma unroll
            for (int r = 0; r < 4; r++) {
                int m = m0 + wm * 64 + mb * 16 + quad * 4 + r;
                int b = m >> 11;
                int s = m & 2047;
                ushort_t val = f2bf(acc[mb][nb][r] + bv);
                if (mat == 0)
                    qws[(((size_t)(b * 16 + h) * SS) + s) * DHEAD + d] = val;
                else if (mat == 1)
                    kws[(((size_t)(b * 16 + h) * SS) + s) * DHEAD + d] = val;
                else
                    vtws[(((size_t)(b * 16 + h) * DHEAD) + d) * SS + s] = val;
            }
        }
    }
}

__global__ __launch_bounds__(256, 2) void dense_gemm_kernel(
    const ushort_t* __restrict__ A,
    const float* __restrict__ W,
    const float* __restrict__ bias,
    float* __restrict__ out)
{
    __shared__ __align__(16) ushort_t As[128 * LDA];
    __shared__ __align__(16) ushort_t Bs[128 * LDA];
    const int tid  = threadIdx.x;
    const int lane = tid & 63;
    const int w    = tid >> 6;
    const int wm   = w >> 1, wn = w & 1;
    const int quad = lane >> 4;
    const int l15  = lane & 15;
    const int m0 = blockIdx.y * 128;
    const int n0 = blockIdx.x * 128;

    f32x4 acc[4][4];
    for (int i = 0; i < 4; i++)
        for (int j = 0; j < 4; j++)
            for (int e = 0; e < 4; e++) acc[i][j][e] = 0.f;

    for (int k0 = 0; k0 < HID; k0 += 32) {
        __syncthreads();
#pragma unroll
        for (int i = 0; i < 2; i++) {
            int chunk = tid + i * 256;
            int row = chunk >> 2, c4 = chunk & 3;
            *(uint4*)(As + row * LDA + c4 * 8) =
                *(const uint4*)(A + (size_t)(m0 + row) * HID + k0 + c4 * 8);
            cvt8(W + (size_t)(n0 + row) * HID + k0 + c4 * 8, Bs + row * LDA + c4 * 8);
        }
        __syncthreads();

        bf16x8 afr[4], bfr[4];
#pragma unroll
        for (int mb = 0; mb < 4; mb++)
            afr[mb] = *(const bf16x8*)(As + (wm * 64 + mb * 16 + l15) * LDA + quad * 8);
#pragma unroll
        for (int nb = 0; nb < 4; nb++)
            bfr[nb] = *(const bf16x8*)(Bs + (wn * 64 + nb * 16 + l15) * LDA + quad * 8);
#pragma unroll
        for (int mb = 0; mb < 4; mb++)
#pragma unroll
            for (int nb = 0; nb < 4; nb++)
                acc[mb][nb] = mfma16(afr[mb], bfr[nb], acc[mb][nb]);
    }

#pragma unroll
    for (int nb = 0; nb < 4; nb++) {
        int n = n0 + wn * 64 + nb * 16 + l15;
        float bv = bias[n];
#pragma unroll
        for (int mb = 0; mb < 4; mb++) {
#pragma unroll
            for (int r = 0; r < 4; r++) {
                int m = m0 + wm * 64 + mb * 16 + quad * 4 + r;
                out[(size_t)m * HID + n] = acc[mb][nb][r] + bv;
            }
        }
    }
}

// ---------------------------------------------------------------------------
// RoPE: trig once per (s,d2), loop over the 32 (b,h) heads.
// ---------------------------------------------------------------------------
__global__ void rope_kernel2(ushort_t* __restrict__ qws, ushort_t* __restrict__ kws)
{
    int idx = blockIdx.x * blockDim.x + threadIdx.x;   // 2048*64 threads
    int d2 = idx & 63;
    int s  = idx >> 6;

    // 10000^(-d2/64) = exp2(-d2/64 * log2(10000))
    float inv_freq = exp2f(-(float)d2 * (13.287712379549449f / 64.f));
    float fr = (float)s * inv_freq;
    float sn, cs;
    sincosf(fr, &sn, &cs);

    size_t base0 = (size_t)s * DHEAD + d2;
#pragma unroll
    for (int bh = 0; bh < BB * NHEAD; bh++) {
        size_t base = base0 + (size_t)bh * (SS * DHEAD);
        float q1 = bf2f(qws[base]);
        float q2 = bf2f(qws[base + 64]);
        qws[base]      = f2bf(q1 * cs - q2 * sn);
        qws[base + 64] = f2bf(q2 * cs + q1 * sn);
        float k1 = bf2f(kws[base]);
        float k2 = bf2f(kws[base + 64]);
        kws[base]      = f2bf(k1 * cs - k2 * sn);
        kws[base + 64] = f2bf(k2 * cs + k1 * sn);
    }
}

// ---------------------------------------------------------------------------
// Causal flash attention, paired q-tiles (tA = blockIdx.x, tB = NT-1-tA).
// Per block: 33 uniform tile-works. Q frags in registers. K/V^T staged via
// async global_load_lds into unpadded XOR-swizzled tiles (chunk cc^(row&7)).
// ---------------------------------------------------------------------------
#define LDP 72

__device__ __forceinline__ void online_softmax(
    f32x4 s_acc[4], float m_st[4], float l_st[4], f32x4 o_acc[8],
    ushort_t* pbuf, int q_row_base, int kb, int l15, int quad)
{
    // scale * log2(e), softmax in exp2 domain
    const float scale2 = 0.12753102015727466f;  // (1/sqrt(128)) * 1.4426950408889634
    float sv[4][4], tmax[4];
#pragma unroll
    for (int r = 0; r < 4; r++) tmax[r] = -1.0e30f;
#pragma unroll
    for (int nb = 0; nb < 4; nb++) {
        int kidx = kb + nb * 16 + l15;
#pragma unroll
        for (int r = 0; r < 4; r++) {
            float v = s_acc[nb][r] * scale2;
            v = (kidx <= q_row_base + r) ? v : -1.0e30f;
            sv[nb][r] = v;
            tmax[r] = fmaxf(tmax[r], v);
        }
    }
#pragma unroll
    for (int r = 0; r < 4; r++) {
        float v = tmax[r];
        v = fmaxf(v, __shfl_xor(v, 1));
        v = fmaxf(v, __shfl_xor(v, 2));
        v = fmaxf(v, __shfl_xor(v, 4));
        v = fmaxf(v, __shfl_xor(v, 8));
        tmax[r] = v;
    }
    float alpha[4], rsum[4];
#pragma unroll
    for (int r = 0; r < 4; r++) {
        float mn = fmaxf(m_st[r], tmax[r]);
        alpha[r] = exp2f(fmaxf(m_st[r] - mn, -120.f));
        m_st[r] = mn;
        rsum[r] = 0.f;
    }
#pragma unroll
    for (int nb = 0; nb < 4; nb++) {
#pragma unroll
        for (int r = 0; r < 4; r++) {
            float p = exp2f(fmaxf(sv[nb][r] - m_st[r], -120.f));
            rsum[r] += p;
            pbuf[(quad * 4 + r) * LDP + nb * 16 + l15] = f2bf(p);
        }
    }
#pragma unroll
    for (int r = 0; r < 4; r++) {
        float v = rsum[r];
        v += __shfl_xor(v, 1);
        v += __shfl_xor(v, 2);
        v += __shfl_xor(v, 4);
        v += __shfl_xor(v, 8);
        l_st[r] = l_st[r] * alpha[r] + v;
    }
#pragma unroll
    for (int i = 0; i < 8; i++)
#pragma unroll
        for (int r = 0; r < 4; r++) o_acc[i][r] *= alpha[r];
}

__global__ __launch_bounds__(256, 2) void attn_kernel2(
    const ushort_t* __restrict__ qws,
    const ushort_t* __restrict__ kws,
    const ushort_t* __restrict__ vtws,
    ushort_t* __restrict__ aout)
{
    __shared__ __align__(16) ushort_t k_s[64 * 128];    // 16 KiB, swizzled
    __shared__ __align__(16) ushort_t vt_s[128 * 64];   // 16 KiB, swizzled
    __shared__ __align__(16) ushort_t pA_s[4][16 * LDP];
    __shared__ __align__(16) ushort_t pB_s[4][16 * LDP];

    const int tid  = threadIdx.x;
    const int lane = tid & 63;
    const int w    = tid >> 6;
    const int quad = lane >> 4;
    const int l15  = lane & 15;

    const int bh = blockIdx.y;
    const int tA = blockIdx.x;          // 0..15
    const int tB = NT - 1 - tA;         // 31..16
    const int qA = tA * 64, qB = tB * 64;
    const size_t qk_base = (size_t)bh * SS * DHEAD;

    // Q fragments in registers (A-layout: m=l15, k=quad*8+j within 32-chunk)
    bf16x8 qa[4], qb[4];
    {
        const ushort_t* rowA = qws + qk_base + (size_t)(qA + w * 16 + l15) * DHEAD;
        const ushort_t* rowB = qws + qk_base + (size_t)(qB + w * 16 + l15) * DHEAD;
#pragma unroll
        for (int kc = 0; kc < 4; kc++) {
            qa[kc] = *(const bf16x8*)(rowA + kc * 32 + quad * 8);
            qb[kc] = *(const bf16x8*)(rowB + kc * 32 + quad * 8);
        }
    }

    float mA[4], lA[4], mB[4], lB[4];
    f32x4 oA[8], oB[8];
#pragma unroll
    for (int r = 0; r < 4; r++) { mA[r] = -1.0e30f; lA[r] = 0.f; mB[r] = -1.0e30f; lB[r] = 0.f; }
#pragma unroll
    for (int i = 0; i < 8; i++)
#pragma unroll
        for (int e = 0; e < 4; e++) { oA[i][e] = 0.f; oB[i][e] = 0.f; }

    // staging lane constants
    const int srowK = lane >> 4;                 // K: 4 rows per pass (quad)
    const int ccgK  = l15 ^ 0;                   // placeholder; K cc below
    const int srowV = lane >> 3;                 // VT: 8 rows per pass
    const int ccgV  = (lane & 7) ^ (lane >> 3);  // VT global chunk (xor swizzle)
    (void)ccgK;

    const int q_baseA = qA + w * 16 + quad * 4;
    const int q_baseB = qB + w * 16 + quad * 4;
    const int xorv = l15 & 7;                    // frag-read swizzle term

    for (int j = 0; j <= tB; j++) {
        const int kb = j * 64;
        __syncthreads();
        // --- stage K tile (64 rows x 128 elems, 16 chunks/row, swizzle cc^(row&7)) ---
#pragma unroll
        for (int i = 0; i < 4; i++) {
            int P = i * 4 + w;                   // 0..15
            int row = P * 4 + srowK;             // 0..63   (row&7 = (P&1)*4+quad)
            int ccg = l15 ^ (((P & 1) * 4) + srowK);
            gload16(kws + qk_base + (size_t)(kb + row) * DHEAD + ccg * 8,
                    k_s + P * 512);
        }
        // --- stage VT tile (128 rows x 64 elems, 8 chunks/row, swizzle cc^(row&7)) ---
#pragma unroll
        for (int i = 0; i < 4; i++) {
            int P = i * 4 + w;                   // 0..15
            int row = P * 8 + srowV;             // 0..127  (row&7 = lane>>3)
            gload16(vtws + qk_base + (size_t)row * SS + kb + ccgV * 8,
                    vt_s + P * 512);
        }
        __syncthreads();

        // --- QK^T (K-frags shared between tiles) ---
        f32x4 sA[4], sB[4];
#pragma unroll
        for (int nb = 0; nb < 4; nb++)
#pragma unroll
            for (int e = 0; e < 4; e++) { sA[nb][e] = 0.f; sB[nb][e] = 0.f; }

        if (j <= tA) {
#pragma unroll
            for (int kc = 0; kc < 4; kc++) {
#pragma unroll
                for (int nb = 0; nb < 4; nb++) {
                    int cc_s = (kc * 4 + quad) ^ xorv;
                    bf16x8 kf = *(const bf16x8*)(k_s + (nb * 16 + l15) * 128 + cc_s * 8);
                    sA[nb] = mfma16(qa[kc], kf, sA[nb]);
                    sB[nb] = mfma16(qb[kc], kf, sB[nb]);
                }
            }
            online_softmax(sA, mA, lA, oA, pA_s[w], q_baseA, kb, l15, quad);
            online_softmax(sB, mB, lB, oB, pB_s[w], q_baseB, kb, l15, quad);
            // --- P·V (V-frags shared) ---
#pragma unroll
            for (int kc = 0; kc < 2; kc++) {
                bf16x8 pa = *(const bf16x8*)(pA_s[w] + l15 * LDP + kc * 32 + quad * 8);
                bf16x8 pb = *(const bf16x8*)(pB_s[w] + l15 * LDP + kc * 32 + quad * 8);
#pragma unroll
                for (int db = 0; db < 8; db++) {
                    int cc_s = (kc * 4 + quad) ^ xorv;
                    bf16x8 vf = *(const bf16x8*)(vt_s + (db * 16 + l15) * 64 + cc_s * 8);
                    oA[db] = mfma16(pa, vf, oA[db]);
                    oB[db] = mfma16(pb, vf, oB[db]);
                }
            }
        } else {
#pragma unroll
            for (int kc = 0; kc < 4; kc++) {
#pragma unroll
                for (int nb = 0; nb < 4; nb++) {
                    int cc_s = (kc * 4 + quad) ^ xorv;
                    bf16x8 kf = *(const bf16x8*)(k_s + (nb * 16 + l15) * 128 + cc_s * 8);
                    sB[nb] = mfma16(qb[kc], kf, sB[nb]);
                }
            }
            online_softmax(sB, mB, lB, oB, pB_s[w], q_baseB, kb, l15, quad);
#pragma unroll
            for (int kc = 0; kc < 2; kc++) {
                bf16x8 pb = *(const bf16x8*)(pB_s[w] + l15 * LDP + kc * 32 + quad * 8);
#pragma unroll
                for (int db = 0; db < 8; db++) {
                    int cc_s = (kc * 4 + quad) ^ xorv;
                    bf16x8 vf = *(const bf16x8*)(vt_s + (db * 16 + l15) * 64 + cc_s * 8);
                    oB[db] = mfma16(pb, vf, oB[db]);
                }
            }
        }
    }

    // --- epilogue: aout[b*S + s][h*128 + d] (bf16) ---
    const int b = bh >> 4;
    const int h = bh & 15;
    float invA[4], invB[4];
#pragma unroll
    for (int r = 0; r < 4; r++) { invA[r] = 1.f / lA[r]; invB[r] = 1.f / lB[r]; }
#pragma unroll
    for (int db = 0; db < 8; db++) {
#pragma unroll
        for (int r = 0; r < 4; r++) {
            int sA_row = qA + w * 16 + quad * 4 + r;
            int sB_row = qB + w * 16 + quad * 4 + r;
            size_t offA = ((size_t)(b * SS + sA_row)) * HID + h * DHEAD + db * 16 + l15;
            size_t offB = ((size_t)(b * SS + sB_row)) * HID + h * DHEAD + db * 16 + l15;
            aout[offA] = f2bf(oA[db][r] * invA[r]);
            aout[offB] = f2bf(oB[db][r] * invB[r]);
        }
    }
}

// ---------------------------------------------------------------------------
extern "C" void kernel_launch(void* const* d_in, const int* in_sizes, int n_in,
                              void* d_out, int out_size, void* d_ws, size_t ws_size,
                              hipStream_t stream)
{
    const float* X    = (const float*)d_in[0];
    const float* Wqkv = (const float*)d_in[1];
    const float* bqkv = (const float*)d_in[2];
    const float* Wd   = (const float*)d_in[3];
    const float* bd   = (const float*)d_in[4];
    float* out = (float*)d_out;

    char* ws = (char*)d_ws;
    const size_t MB = 1048576;
    ushort_t* qws  = (ushort_t*)(ws);              // 16 MiB [B,H,S,D] bf16
    ushort_t* kws  = (ushort_t*)(ws + 16 * MB);    // 16 MiB
    ushort_t* vtws = (ushort_t*)(ws + 32 * MB);    // 16 MiB [B,H,D,S]
    ushort_t* aout = (ushort_t*)(ws + 48 * MB);    // 16 MiB [B*S,HID] (aliases Xbf)

    if (ws_size >= 96 * MB) {
        ushort_t* Xbf  = (ushort_t*)(ws + 48 * MB);   // dead after qkv; aout reuses
        ushort_t* Wqbf = (ushort_t*)(ws + 64 * MB);   // 24 MiB
        ushort_t* Wdbf = (ushort_t*)(ws + 88 * MB);   // 8 MiB

        cvt_kernel<<<(MM * HID / 8 + 255) / 256, 256, 0, stream>>>(X, Xbf, MM * HID / 8);
        cvt_kernel<<<(NQKV * HID / 8 + 255) / 256, 256, 0, stream>>>(Wqkv, Wqbf, NQKV * HID / 8);
        cvt_kernel<<<(HID * HID / 8 + 255) / 256, 256, 0, stream>>>(Wd, Wdbf, HID * HID / 8);

        qkv_gemm_fast<<<dim3(NQKV / 128, MM / 128), 256, 0, stream>>>(Xbf, Wqbf, bqkv, qws, kws, vtws);
        rope_kernel2<<<(SS * 64) / 256, 256, 0, stream>>>(qws, kws);
        attn_kernel2<<<dim3(NT / 2, BB * NHEAD), 256, 0, stream>>>(qws, kws, vtws, aout);
        dense_gemm_fast<<<dim3(HID / 128, MM / 128), 256, 0, stream>>>(aout, Wdbf, bd, out);
    } else {
        qkv_gemm_kernel<<<dim3(NQKV / 128, MM / 128), 256, 0, stream>>>(X, Wqkv, bqkv, qws, kws, vtws);
        rope_kernel2<<<(SS * 64) / 256, 256, 0, stream>>>(qws, kws);
        attn_kernel2<<<dim3(NT / 2, BB * NHEAD), 256, 0, stream>>>(qws, kws, vtws, aout);
        dense_gemm_kernel<<<dim3(HID / 128, MM / 128), 256, 0, stream>>>(aout, Wd, bd, out);
    }
}